// Round 1
// baseline (419.152 us; speedup 1.0000x reference)
//
#include <hip/hip_runtime.h>
#include <hip/hip_bf16.h>
#include <math.h>

#define NS 4096          // samples per view
#define NI 8192          // total instances (2 views)
#define DIM 512
#define TEMP_INV 2.0f    // 1/t, t = 0.5

typedef short v8s __attribute__((ext_vector_type(8)));   // 8 bf16 (4 VGPRs)
typedef float v4f __attribute__((ext_vector_type(4)));   // 4 fp32 acc

// ---------------------------------------------------------------------------
// Kernel 1: per-sample norms, positive-pair dots (fp32), cast X -> bf16
// block i handles sample pair (x1[i], x2[i]); 256 threads, 2 cols/thread/row
// ---------------------------------------------------------------------------
__global__ __launch_bounds__(256) void prep_kernel(
        const float* __restrict__ x1, const float* __restrict__ x2,
        __hip_bfloat16* __restrict__ Xb, float* __restrict__ rnorm,
        float* __restrict__ posdot) {
    const int i = blockIdx.x;
    const int t = threadIdx.x;
    const float* r1 = x1 + (size_t)i * DIM;
    const float* r2 = x2 + (size_t)i * DIM;
    float s1 = 0.f, s2 = 0.f, dd = 0.f;
    #pragma unroll
    for (int c = t; c < DIM; c += 256) {
        float a = r1[c], b = r2[c];
        s1 += a * a; s2 += b * b; dd += a * b;
        Xb[(size_t)i * DIM + c]        = __float2bfloat16(a);
        Xb[(size_t)(i + NS) * DIM + c] = __float2bfloat16(b);
    }
    __shared__ float red[3][4];
    #pragma unroll
    for (int off = 32; off; off >>= 1) {
        s1 += __shfl_down(s1, off, 64);
        s2 += __shfl_down(s2, off, 64);
        dd += __shfl_down(dd, off, 64);
    }
    if ((t & 63) == 0) { int w = t >> 6; red[0][w] = s1; red[1][w] = s2; red[2][w] = dd; }
    __syncthreads();
    if (t == 0) {
        s1 = red[0][0] + red[0][1] + red[0][2] + red[0][3];
        s2 = red[1][0] + red[1][1] + red[1][2] + red[1][3];
        dd = red[2][0] + red[2][1] + red[2][2] + red[2][3];
        rnorm[i]      = 1.0f / sqrtf(s1);
        rnorm[i + NS] = 1.0f / sqrtf(s2);
        posdot[i] = dd;
    }
}

// ---------------------------------------------------------------------------
// Kernel 2: G = Xb*Xb^T in 128x128 tiles via mfma_f32_16x16x32_bf16.
// Fragments loaded directly from global (Xb is L2/L3 resident, 8 MB).
// Epilogue: sim2 = 2 * D * r_i * r_j; masked entries (j==i, j==i^4096)
// contribute exp(0)=1 to row sums and 0 to the global neg-sim sum.
// A-frag: lane holds A[m=lane&15][k=(lane>>4)*8 + j]; B-frag identical form
// (B^T = X row-major). C/D: col=lane&15, row=(lane>>4)*4+reg.
// ---------------------------------------------------------------------------
__global__ __launch_bounds__(256) void sim_kernel(
        const __hip_bfloat16* __restrict__ Xbh, const float* __restrict__ rnorm,
        float* __restrict__ rowsum, float* __restrict__ negsum) {
    const int i0 = blockIdx.y * 128;
    const int j0 = blockIdx.x * 128;
    const int t = threadIdx.x;
    const int lane = t & 63, wv = t >> 6;
    const int wr = wv >> 1, wc = wv & 1;       // 2x2 waves, each 64x64
    const int r16 = lane & 15, quad = lane >> 4;

    const short* X = reinterpret_cast<const short*>(Xbh);
    const short* arow[4];
    const short* brow[4];
    #pragma unroll
    for (int tt = 0; tt < 4; ++tt) {
        arow[tt] = X + (size_t)(i0 + wr * 64 + tt * 16 + r16) * DIM + quad * 8;
        brow[tt] = X + (size_t)(j0 + wc * 64 + tt * 16 + r16) * DIM + quad * 8;
    }

    v4f acc[4][4];
    #pragma unroll
    for (int a = 0; a < 4; ++a)
        #pragma unroll
        for (int b = 0; b < 4; ++b)
            acc[a][b] = (v4f){0.f, 0.f, 0.f, 0.f};

    for (int k0 = 0; k0 < DIM; k0 += 32) {
        v8s af[4], bf[4];
        #pragma unroll
        for (int tt = 0; tt < 4; ++tt) af[tt] = *(const v8s*)(arow[tt] + k0);
        #pragma unroll
        for (int tt = 0; tt < 4; ++tt) bf[tt] = *(const v8s*)(brow[tt] + k0);
        #pragma unroll
        for (int ta = 0; ta < 4; ++ta)
            #pragma unroll
            for (int tb = 0; tb < 4; ++tb)
                acc[ta][tb] = __builtin_amdgcn_mfma_f32_16x16x32_bf16(
                    af[ta], bf[tb], acc[ta][tb], 0, 0, 0);
    }

    // epilogue
    float rc[4];
    int colg[4];
    #pragma unroll
    for (int tb = 0; tb < 4; ++tb) {
        colg[tb] = j0 + wc * 64 + tb * 16 + r16;
        rc[tb] = rnorm[colg[tb]];
    }
    float negacc = 0.f;
    #pragma unroll
    for (int ta = 0; ta < 4; ++ta) {
        #pragma unroll
        for (int r = 0; r < 4; ++r) {
            const int rowg = i0 + wr * 64 + ta * 16 + quad * 4 + r;
            const float rr = rnorm[rowg] * TEMP_INV;
            float rowe = 0.f;
            #pragma unroll
            for (int tb = 0; tb < 4; ++tb) {
                float sim2 = acc[ta][tb][r] * rr * rc[tb];
                bool masked = (colg[tb] == rowg) || (colg[tb] == (rowg ^ NS));
                rowe   += masked ? 1.0f : __expf(sim2);
                negacc += masked ? 0.0f : sim2;
            }
            // reduce the 16 lanes holding this row's 16 columns (within quad)
            #pragma unroll
            for (int off = 1; off < 16; off <<= 1)
                rowe += __shfl_xor(rowe, off, 64);
            if (r16 == 0) atomicAdd(&rowsum[rowg], rowe);
        }
    }
    #pragma unroll
    for (int off = 1; off < 64; off <<= 1)
        negacc += __shfl_xor(negacc, off, 64);
    if (lane == 0) atomicAdd(negsum, negacc);
}

// ---------------------------------------------------------------------------
// Kernel 3: final scalars.
// loss_i = log(exp(s_pos_i) + E_i) - s_pos_i ; E_i = rowsum[i] (already
// includes the +2 from the two masked entries).
// ---------------------------------------------------------------------------
__global__ __launch_bounds__(256) void final_kernel(
        const float* __restrict__ rowsum, const float* __restrict__ rnorm,
        const float* __restrict__ posdot, const float* __restrict__ negsum,
        float* __restrict__ out) {
    const int t = threadIdx.x;
    float lsum = 0.f, psum = 0.f;
    for (int i = t; i < NI; i += 256) {
        const int s = i & (NS - 1);
        const float sp = posdot[s] * rnorm[i] * rnorm[i ^ NS] * TEMP_INV;
        const float E = rowsum[i];
        lsum += logf(expf(sp) + E) - sp;
        psum += sp;
    }
    __shared__ float red[2][4];
    #pragma unroll
    for (int off = 32; off; off >>= 1) {
        lsum += __shfl_down(lsum, off, 64);
        psum += __shfl_down(psum, off, 64);
    }
    if ((t & 63) == 0) { red[0][t >> 6] = lsum; red[1][t >> 6] = psum; }
    __syncthreads();
    if (t == 0) {
        lsum = red[0][0] + red[0][1] + red[0][2] + red[0][3];
        psum = red[1][0] + red[1][1] + red[1][2] + red[1][3];
        out[0] = lsum / (float)NI;
        out[1] = psum / (float)NI;
        out[2] = *negsum / ((float)NI * (float)(NI - 2));
    }
}

// ---------------------------------------------------------------------------
extern "C" void kernel_launch(void* const* d_in, const int* in_sizes, int n_in,
                              void* d_out, int out_size, void* d_ws, size_t ws_size,
                              hipStream_t stream) {
    const float* x1 = (const float*)d_in[0];
    const float* x2 = (const float*)d_in[1];
    float* out = (float*)d_out;

    char* ws = (char*)d_ws;
    __hip_bfloat16* Xb = (__hip_bfloat16*)ws;                 // NI*DIM*2 = 8 MB
    float* rnorm  = (float*)(ws + (size_t)NI * DIM * 2);      // NI
    float* posdot = rnorm + NI;                               // NS
    float* rowsum = posdot + NS;                              // NI
    float* negsum = rowsum + NI;                              // 1

    // ws is poisoned 0xAA each launch: zero the accumulators
    hipMemsetAsync(rowsum, 0, (NI + 1) * sizeof(float), stream);

    prep_kernel<<<NS, 256, 0, stream>>>(x1, x2, Xb, rnorm, posdot);

    dim3 grid(NI / 128, NI / 128);
    sim_kernel<<<grid, 256, 0, stream>>>(Xb, rnorm, rowsum, negsum);

    final_kernel<<<1, 256, 0, stream>>>(rowsum, rnorm, posdot, negsum, out);
}

// Round 2
// 231.918 us; speedup vs baseline: 1.8073x; 1.8073x over previous
//
#include <hip/hip_runtime.h>
#include <hip/hip_bf16.h>
#include <math.h>

#define NS 4096          // samples per view
#define NI 8192          // total instances (2 views)
#define DIM 512
#define TEMP_INV 2.0f    // 1/t, t = 0.5

typedef short v8s __attribute__((ext_vector_type(8)));   // 8 bf16 (4 VGPRs)
typedef float v4f __attribute__((ext_vector_type(4)));   // 4 fp32 acc

// async global->LDS, 16B per lane. LDS dest is wave-uniform base + lane*16.
__device__ __forceinline__ void gld16(const void* g, void* l) {
    __builtin_amdgcn_global_load_lds(
        (const __attribute__((address_space(1))) void*)g,
        (__attribute__((address_space(3))) void*)l, 16, 0, 0);
}

// ---------------------------------------------------------------------------
// Kernel 1: norms + positive dots (fp32), cast X -> bf16. 2 samples/block,
// 128 threads/sample, float4 loads (16B/lane).
// ---------------------------------------------------------------------------
__global__ __launch_bounds__(256) void prep_kernel(
        const float* __restrict__ x1, const float* __restrict__ x2,
        __hip_bfloat16* __restrict__ Xb, float* __restrict__ rnorm,
        float* __restrict__ posdot) {
    const int t = threadIdx.x;
    const int sub = t >> 7;                 // which sample of the pair
    const int c4 = t & 127;                 // float4 column
    const int i = blockIdx.x * 2 + sub;
    const float4 a = ((const float4*)(x1 + (size_t)i * DIM))[c4];
    const float4 b = ((const float4*)(x2 + (size_t)i * DIM))[c4];
    float s1 = a.x*a.x + a.y*a.y + a.z*a.z + a.w*a.w;
    float s2 = b.x*b.x + b.y*b.y + b.z*b.z + b.w*b.w;
    float dd = a.x*b.x + a.y*b.y + a.z*b.z + a.w*b.w;

    auto bfbits = [](float v) -> unsigned short {
        __hip_bfloat16 h = __float2bfloat16(v);
        return *(unsigned short*)&h;
    };
    ushort4 pa = { bfbits(a.x), bfbits(a.y), bfbits(a.z), bfbits(a.w) };
    ushort4 pb = { bfbits(b.x), bfbits(b.y), bfbits(b.z), bfbits(b.w) };
    ((ushort4*)(Xb + (size_t)i * DIM))[c4] = pa;
    ((ushort4*)(Xb + (size_t)(i + NS) * DIM))[c4] = pb;

    #pragma unroll
    for (int off = 32; off; off >>= 1) {
        s1 += __shfl_down(s1, off, 64);
        s2 += __shfl_down(s2, off, 64);
        dd += __shfl_down(dd, off, 64);
    }
    __shared__ float red[2][2][3];
    if ((t & 63) == 0) {
        const int w = (t >> 6) & 1;
        red[sub][w][0] = s1; red[sub][w][1] = s2; red[sub][w][2] = dd;
    }
    __syncthreads();
    if ((t & 127) == 0) {
        s1 = red[sub][0][0] + red[sub][1][0];
        s2 = red[sub][0][1] + red[sub][1][1];
        dd = red[sub][0][2] + red[sub][1][2];
        rnorm[i]      = 1.0f / sqrtf(s1);
        rnorm[i + NS] = 1.0f / sqrtf(s2);
        posdot[i] = dd;
    }
}

// ---------------------------------------------------------------------------
// Kernel 2: upper-triangle 128x128 tiles of G = Xb*Xb^T via
// mfma_f32_16x16x32_bf16, m97-style LDS staging with global_load_lds(16B).
// LDS layout: [128 rows][32 k] bf16, 64 B/row, with the 4 16B k-chunks
// XOR-swizzled by ((row>>1)&3) so ds_read_b128 is 2-way bank-aliased (free).
// Off-diagonal tiles (bj>bi) add exp-sums to BOTH rowsum[row] and rowsum[col]
// and count sim twice in negsum (G symmetric, mask symmetric).
// ---------------------------------------------------------------------------
__global__ __launch_bounds__(256) void sim_kernel(
        const __hip_bfloat16* __restrict__ Xbh, const float* __restrict__ rnorm,
        float* __restrict__ rowsum, float* __restrict__ negsum) {
    const int bi = blockIdx.y, bj = blockIdx.x;
    if (bj < bi) return;                       // lower triangle: skip
    const bool offdiag = (bj != bi);
    const int i0 = bi * 128, j0 = bj * 128;

    __shared__ short lA[128 * 32];             // 8 KB
    __shared__ short lB[128 * 32];             // 8 KB

    const int t = threadIdx.x;
    const int lane = t & 63, wv = t >> 6;
    const int wr = wv >> 1, wc = wv & 1;       // 2x2 waves, each 64x64
    const int r16 = lane & 15, quad = lane >> 4;

    const short* X = reinterpret_cast<const short*>(Xbh);

    // --- staging addresses: wave wv owns 1KB chunks {wv*2, wv*2+1} of each tile
    const short* gA[2]; const short* gB[2]; int ldst[2];
    #pragma unroll
    for (int q = 0; q < 2; ++q) {
        const int c = wv * 2 + q;
        const int r_loc = c * 16 + (lane >> 2);          // row within tile
        const int kc_l = (lane & 3) ^ ((r_loc >> 1) & 3); // logical 16B k-chunk
        gA[q] = X + (size_t)(i0 + r_loc) * DIM + kc_l * 8;
        gB[q] = X + (size_t)(j0 + r_loc) * DIM + kc_l * 8;
        ldst[q] = c * 512;                                // shorts (1KB chunks)
    }

    // --- fragment LDS byte offsets (swizzled)
    int offA[4], offB[4];
    #pragma unroll
    for (int tt = 0; tt < 4; ++tt) {
        const int tra = wr * 64 + tt * 16 + r16;
        offA[tt] = tra * 64 + ((quad ^ ((tra >> 1) & 3)) * 16);
        const int trb = wc * 64 + tt * 16 + r16;
        offB[tt] = trb * 64 + ((quad ^ ((trb >> 1) & 3)) * 16);
    }

    v4f acc[4][4];
    #pragma unroll
    for (int a = 0; a < 4; ++a)
        #pragma unroll
        for (int b = 0; b < 4; ++b)
            acc[a][b] = (v4f){0.f, 0.f, 0.f, 0.f};

    for (int k0 = 0; k0 < DIM; k0 += 32) {
        __syncthreads();                       // prior reads done before overwrite
        #pragma unroll
        for (int q = 0; q < 2; ++q) {
            gld16(gA[q] + k0, lA + ldst[q]);
            gld16(gB[q] + k0, lB + ldst[q]);
        }
        __syncthreads();                       // vmcnt(0) drain + barrier
        v8s af[4], bf[4];
        #pragma unroll
        for (int tt = 0; tt < 4; ++tt) {
            af[tt] = *(const v8s*)((const char*)lA + offA[tt]);
            bf[tt] = *(const v8s*)((const char*)lB + offB[tt]);
        }
        #pragma unroll
        for (int ta = 0; ta < 4; ++ta)
            #pragma unroll
            for (int tb = 0; tb < 4; ++tb)
                acc[ta][tb] = __builtin_amdgcn_mfma_f32_16x16x32_bf16(
                    af[ta], bf[tb], acc[ta][tb], 0, 0, 0);
    }

    // --- epilogue
    float rc[4];
    int colg[4];
    #pragma unroll
    for (int tb = 0; tb < 4; ++tb) {
        colg[tb] = j0 + wc * 64 + tb * 16 + r16;
        rc[tb] = rnorm[colg[tb]];
    }
    float negacc = 0.f;
    float colacc[4] = {0.f, 0.f, 0.f, 0.f};
    #pragma unroll
    for (int ta = 0; ta < 4; ++ta) {
        #pragma unroll
        for (int r = 0; r < 4; ++r) {
            const int rowg = i0 + wr * 64 + ta * 16 + quad * 4 + r;
            const float rr = rnorm[rowg] * TEMP_INV;
            float rowe = 0.f;
            #pragma unroll
            for (int tb = 0; tb < 4; ++tb) {
                const float sim2 = acc[ta][tb][r] * rr * rc[tb];
                const bool masked = (colg[tb] == rowg) || (colg[tb] == (rowg ^ NS));
                const float e = masked ? 1.0f : __expf(sim2);
                rowe   += e;
                negacc += masked ? 0.0f : sim2;
                colacc[tb] += e;               // only used for offdiag
            }
            #pragma unroll
            for (int off = 1; off < 16; off <<= 1)
                rowe += __shfl_xor(rowe, off, 64);
            if (r16 == 0) atomicAdd(&rowsum[rowg], rowe);
        }
    }
    if (offdiag) {
        #pragma unroll
        for (int tb = 0; tb < 4; ++tb) {
            colacc[tb] += __shfl_xor(colacc[tb], 16, 64);
            colacc[tb] += __shfl_xor(colacc[tb], 32, 64);
            if (quad == 0) atomicAdd(&rowsum[colg[tb]], colacc[tb]);
        }
        negacc *= 2.0f;
    }
    #pragma unroll
    for (int off = 1; off < 64; off <<= 1)
        negacc += __shfl_xor(negacc, off, 64);
    if (lane == 0) atomicAdd(negsum, negacc);
}

// ---------------------------------------------------------------------------
// Kernel 3: final scalars. E_i = rowsum[i] (includes +2 from masked entries).
// ---------------------------------------------------------------------------
__global__ __launch_bounds__(1024) void final_kernel(
        const float* __restrict__ rowsum, const float* __restrict__ rnorm,
        const float* __restrict__ posdot, const float* __restrict__ negsum,
        float* __restrict__ out) {
    const int t = threadIdx.x;
    float lsum = 0.f, psum = 0.f;
    #pragma unroll
    for (int i = t; i < NI; i += 1024) {
        const int s = i & (NS - 1);
        const float sp = posdot[s] * rnorm[i] * rnorm[i ^ NS] * TEMP_INV;
        const float E = rowsum[i];
        lsum += logf(expf(sp) + E) - sp;
        psum += sp;
    }
    __shared__ float red[2][16];
    #pragma unroll
    for (int off = 32; off; off >>= 1) {
        lsum += __shfl_down(lsum, off, 64);
        psum += __shfl_down(psum, off, 64);
    }
    if ((t & 63) == 0) { red[0][t >> 6] = lsum; red[1][t >> 6] = psum; }
    __syncthreads();
    if (t == 0) {
        lsum = 0.f; psum = 0.f;
        #pragma unroll
        for (int w = 0; w < 16; ++w) { lsum += red[0][w]; psum += red[1][w]; }
        out[0] = lsum / (float)NI;
        out[1] = psum / (float)NI;
        out[2] = *negsum / ((float)NI * (float)(NI - 2));
    }
}

// ---------------------------------------------------------------------------
extern "C" void kernel_launch(void* const* d_in, const int* in_sizes, int n_in,
                              void* d_out, int out_size, void* d_ws, size_t ws_size,
                              hipStream_t stream) {
    const float* x1 = (const float*)d_in[0];
    const float* x2 = (const float*)d_in[1];
    float* out = (float*)d_out;

    char* ws = (char*)d_ws;
    __hip_bfloat16* Xb = (__hip_bfloat16*)ws;                 // NI*DIM*2 = 8 MB
    float* rnorm  = (float*)(ws + (size_t)NI * DIM * 2);      // NI
    float* posdot = rnorm + NI;                               // NS
    float* rowsum = posdot + NS;                              // NI
    float* negsum = rowsum + NI;                              // 1

    // ws is poisoned 0xAA each launch: zero the accumulators
    hipMemsetAsync(rowsum, 0, (NI + 1) * sizeof(float), stream);

    prep_kernel<<<NS / 2, 256, 0, stream>>>(x1, x2, Xb, rnorm, posdot);

    dim3 grid(NI / 128, NI / 128);
    sim_kernel<<<grid, 256, 0, stream>>>(Xb, rnorm, rowsum, negsum);

    final_kernel<<<1, 1024, 0, stream>>>(rowsum, rnorm, posdot, negsum, out);
}

// Round 3
// 163.203 us; speedup vs baseline: 2.5683x; 1.4210x over previous
//
#include <hip/hip_runtime.h>
#include <hip/hip_bf16.h>
#include <math.h>

#define NS 4096          // samples per view
#define NI 8192          // total instances (2 views)
#define DIM 512
#define TEMP_INV 2.0f    // 1/t, t = 0.5
#define NBLK 64          // NI/128 tile blocks per side

typedef short v8s __attribute__((ext_vector_type(8)));   // 8 bf16 (4 VGPRs)
typedef float v4f __attribute__((ext_vector_type(4)));   // 4 fp32 acc

// async global->LDS, 16B per lane. LDS dest is wave-uniform base + lane*16.
__device__ __forceinline__ void gld16(const void* g, void* l) {
    __builtin_amdgcn_global_load_lds(
        (const __attribute__((address_space(1))) void*)g,
        (__attribute__((address_space(3))) void*)l, 16, 0, 0);
}

// ---------------------------------------------------------------------------
// Kernel 1: norms + positive dots (fp32), cast X -> bf16. 2 samples/block.
// ---------------------------------------------------------------------------
__global__ __launch_bounds__(256) void prep_kernel(
        const float* __restrict__ x1, const float* __restrict__ x2,
        __hip_bfloat16* __restrict__ Xb, float* __restrict__ rnorm,
        float* __restrict__ posdot) {
    const int t = threadIdx.x;
    const int sub = t >> 7;                 // which sample of the pair
    const int c4 = t & 127;                 // float4 column
    const int i = blockIdx.x * 2 + sub;
    const float4 a = ((const float4*)(x1 + (size_t)i * DIM))[c4];
    const float4 b = ((const float4*)(x2 + (size_t)i * DIM))[c4];
    float s1 = a.x*a.x + a.y*a.y + a.z*a.z + a.w*a.w;
    float s2 = b.x*b.x + b.y*b.y + b.z*b.z + b.w*b.w;
    float dd = a.x*b.x + a.y*b.y + a.z*b.z + a.w*b.w;

    auto bfbits = [](float v) -> unsigned short {
        __hip_bfloat16 h = __float2bfloat16(v);
        return *(unsigned short*)&h;
    };
    ushort4 pa = { bfbits(a.x), bfbits(a.y), bfbits(a.z), bfbits(a.w) };
    ushort4 pb = { bfbits(b.x), bfbits(b.y), bfbits(b.z), bfbits(b.w) };
    ((ushort4*)(Xb + (size_t)i * DIM))[c4] = pa;
    ((ushort4*)(Xb + (size_t)(i + NS) * DIM))[c4] = pb;

    #pragma unroll
    for (int off = 32; off; off >>= 1) {
        s1 += __shfl_down(s1, off, 64);
        s2 += __shfl_down(s2, off, 64);
        dd += __shfl_down(dd, off, 64);
    }
    __shared__ float red[2][2][3];
    if ((t & 63) == 0) {
        const int w = (t >> 6) & 1;
        red[sub][w][0] = s1; red[sub][w][1] = s2; red[sub][w][2] = dd;
    }
    __syncthreads();
    if ((t & 127) == 0) {
        s1 = red[sub][0][0] + red[sub][1][0];
        s2 = red[sub][0][1] + red[sub][1][1];
        dd = red[sub][0][2] + red[sub][1][2];
        rnorm[i]      = 1.0f / sqrtf(s1);
        rnorm[i + NS] = 1.0f / sqrtf(s2);
        posdot[i] = dd;
    }
}

// ---------------------------------------------------------------------------
// Kernel 2: upper-triangle 128x128 tiles of G = Xb*Xb^T.
// NO same-address atomics: negsum partial -> negpart[bid] (plain store);
// rowsum atomics combined across wave pairs via LDS, 256 distinct-address
// atomics per block issued by 2 coalesced waves.
// ---------------------------------------------------------------------------
__global__ __launch_bounds__(256) void sim_kernel(
        const __hip_bfloat16* __restrict__ Xbh, const float* __restrict__ rnorm,
        float* __restrict__ rowsum, float* __restrict__ negpart) {
    const int bi = blockIdx.y, bj = blockIdx.x;
    if (bj < bi) return;                       // lower triangle: skip
    const bool offdiag = (bj != bi);
    const int i0 = bi * 128, j0 = bj * 128;

    __shared__ short lA[128 * 32];             // 8 KB
    __shared__ short lB[128 * 32];             // 8 KB
    __shared__ float sRowAll[2][128];          // 1 KB  [wc][row]
    __shared__ float sColAll[2][128];          // 1 KB  [wr][col]
    __shared__ float sNeg[4];

    const int t = threadIdx.x;
    const int lane = t & 63, wv = t >> 6;
    const int wr = wv >> 1, wc = wv & 1;       // 2x2 waves, each 64x64
    const int r16 = lane & 15, quad = lane >> 4;

    const short* X = reinterpret_cast<const short*>(Xbh);

    // --- staging addresses: wave wv owns 1KB chunks {wv*2, wv*2+1} of each tile
    const short* gA[2]; const short* gB[2]; int ldst[2];
    #pragma unroll
    for (int q = 0; q < 2; ++q) {
        const int c = wv * 2 + q;
        const int r_loc = c * 16 + (lane >> 2);           // row within tile
        const int kc_l = (lane & 3) ^ ((r_loc >> 1) & 3); // swizzled 16B k-chunk
        gA[q] = X + (size_t)(i0 + r_loc) * DIM + kc_l * 8;
        gB[q] = X + (size_t)(j0 + r_loc) * DIM + kc_l * 8;
        ldst[q] = c * 512;
    }

    // --- fragment LDS byte offsets (swizzled)
    int offA[4], offB[4];
    #pragma unroll
    for (int tt = 0; tt < 4; ++tt) {
        const int tra = wr * 64 + tt * 16 + r16;
        offA[tt] = tra * 64 + ((quad ^ ((tra >> 1) & 3)) * 16);
        const int trb = wc * 64 + tt * 16 + r16;
        offB[tt] = trb * 64 + ((quad ^ ((trb >> 1) & 3)) * 16);
    }

    v4f acc[4][4];
    #pragma unroll
    for (int a = 0; a < 4; ++a)
        #pragma unroll
        for (int b = 0; b < 4; ++b)
            acc[a][b] = (v4f){0.f, 0.f, 0.f, 0.f};

    for (int k0 = 0; k0 < DIM; k0 += 32) {
        __syncthreads();
        #pragma unroll
        for (int q = 0; q < 2; ++q) {
            gld16(gA[q] + k0, lA + ldst[q]);
            gld16(gB[q] + k0, lB + ldst[q]);
        }
        __syncthreads();
        v8s af[4], bf[4];
        #pragma unroll
        for (int tt = 0; tt < 4; ++tt) {
            af[tt] = *(const v8s*)((const char*)lA + offA[tt]);
            bf[tt] = *(const v8s*)((const char*)lB + offB[tt]);
        }
        #pragma unroll
        for (int ta = 0; ta < 4; ++ta)
            #pragma unroll
            for (int tb = 0; tb < 4; ++tb)
                acc[ta][tb] = __builtin_amdgcn_mfma_f32_16x16x32_bf16(
                    af[ta], bf[tb], acc[ta][tb], 0, 0, 0);
    }

    // --- epilogue: sim2 = 2*D*r_i*r_j; masked (j==i, j==i^NS) -> exp contributes 1
    float rc[4];
    int colg[4];
    #pragma unroll
    for (int tb = 0; tb < 4; ++tb) {
        colg[tb] = j0 + wc * 64 + tb * 16 + r16;
        rc[tb] = rnorm[colg[tb]];
    }
    float negacc = 0.f;
    float colacc[4] = {0.f, 0.f, 0.f, 0.f};
    #pragma unroll
    for (int ta = 0; ta < 4; ++ta) {
        #pragma unroll
        for (int r = 0; r < 4; ++r) {
            const int rowl = wr * 64 + ta * 16 + quad * 4 + r;
            const int rowg = i0 + rowl;
            const float rr = rnorm[rowg] * TEMP_INV;
            float rowe = 0.f;
            #pragma unroll
            for (int tb = 0; tb < 4; ++tb) {
                const float sim2 = acc[ta][tb][r] * rr * rc[tb];
                const bool masked = (colg[tb] == rowg) || (colg[tb] == (rowg ^ NS));
                const float e = masked ? 1.0f : __expf(sim2);
                rowe   += e;
                negacc += masked ? 0.0f : sim2;
                colacc[tb] += e;
            }
            #pragma unroll
            for (int off = 1; off < 16; off <<= 1)
                rowe += __shfl_xor(rowe, off, 64);
            if (r16 == 0) sRowAll[wc][rowl] = rowe;   // LDS, combined later
        }
    }
    // col partials: reduce over the 4 quads (rows) within wave
    #pragma unroll
    for (int tb = 0; tb < 4; ++tb) {
        colacc[tb] += __shfl_xor(colacc[tb], 16, 64);
        colacc[tb] += __shfl_xor(colacc[tb], 32, 64);
        if (quad == 0) sColAll[wr][wc * 64 + tb * 16 + r16] = colacc[tb];
    }
    // block negsum partial
    if (offdiag) negacc *= 2.0f;
    #pragma unroll
    for (int off = 1; off < 64; off <<= 1)
        negacc += __shfl_xor(negacc, off, 64);
    if (lane == 0) sNeg[wv] = negacc;

    __syncthreads();

    if (t < 128) {
        atomicAdd(&rowsum[i0 + t], sRowAll[0][t] + sRowAll[1][t]);
        if (offdiag)
            atomicAdd(&rowsum[j0 + t], sColAll[0][t] + sColAll[1][t]);
    }
    if (t == 0)
        negpart[bi * NBLK + bj] = sNeg[0] + sNeg[1] + sNeg[2] + sNeg[3];
}

// ---------------------------------------------------------------------------
// Kernel 3: final scalars. E_i = rowsum[i] (includes +2 from masked entries).
// ---------------------------------------------------------------------------
__global__ __launch_bounds__(1024) void final_kernel(
        const float* __restrict__ rowsum, const float* __restrict__ rnorm,
        const float* __restrict__ posdot, const float* __restrict__ negpart,
        float* __restrict__ out) {
    const int t = threadIdx.x;
    float lsum = 0.f, psum = 0.f, nsum = 0.f;
    #pragma unroll
    for (int i = t; i < NI; i += 1024) {
        const int s = i & (NS - 1);
        const float sp = posdot[s] * rnorm[i] * rnorm[i ^ NS] * TEMP_INV;
        const float E = rowsum[i];
        lsum += logf(expf(sp) + E) - sp;
        psum += sp;
    }
    #pragma unroll
    for (int i = t; i < NBLK * NBLK; i += 1024)
        nsum += negpart[i];
    __shared__ float red[3][16];
    #pragma unroll
    for (int off = 32; off; off >>= 1) {
        lsum += __shfl_down(lsum, off, 64);
        psum += __shfl_down(psum, off, 64);
        nsum += __shfl_down(nsum, off, 64);
    }
    if ((t & 63) == 0) {
        red[0][t >> 6] = lsum; red[1][t >> 6] = psum; red[2][t >> 6] = nsum;
    }
    __syncthreads();
    if (t == 0) {
        lsum = 0.f; psum = 0.f; nsum = 0.f;
        #pragma unroll
        for (int w = 0; w < 16; ++w) {
            lsum += red[0][w]; psum += red[1][w]; nsum += red[2][w];
        }
        out[0] = lsum / (float)NI;
        out[1] = psum / (float)NI;
        out[2] = nsum / ((float)NI * (float)(NI - 2));
    }
}

// ---------------------------------------------------------------------------
extern "C" void kernel_launch(void* const* d_in, const int* in_sizes, int n_in,
                              void* d_out, int out_size, void* d_ws, size_t ws_size,
                              hipStream_t stream) {
    const float* x1 = (const float*)d_in[0];
    const float* x2 = (const float*)d_in[1];
    float* out = (float*)d_out;

    char* ws = (char*)d_ws;
    __hip_bfloat16* Xb = (__hip_bfloat16*)ws;                 // NI*DIM*2 = 8 MB
    float* rnorm  = (float*)(ws + (size_t)NI * DIM * 2);      // NI
    float* posdot = rnorm + NI;                               // NS
    float* rowsum = posdot + NS;                              // NI
    float* negpart = rowsum + NI;                             // NBLK*NBLK

    // ws is poisoned 0xAA each launch: zero the accumulators
    hipMemsetAsync(rowsum, 0, (NI + NBLK * NBLK) * sizeof(float), stream);

    prep_kernel<<<NS / 2, 256, 0, stream>>>(x1, x2, Xb, rnorm, posdot);

    dim3 grid(NBLK, NBLK);
    sim_kernel<<<grid, 256, 0, stream>>>(Xb, rnorm, rowsum, negpart);

    final_kernel<<<1, 1024, 0, stream>>>(rowsum, rnorm, posdot, negpart, out);
}

// Round 4
// 135.482 us; speedup vs baseline: 3.0938x; 1.2046x over previous
//
#include <hip/hip_runtime.h>
#include <hip/hip_bf16.h>
#include <math.h>

#define NS 4096          // samples per view
#define NI 8192          // total instances (2 views)
#define DIM 512
#define TEMP_INV 2.0f    // 1/t, t = 0.5
#define NBLK 64          // NI/128 tile blocks per side
#define NTRI (NBLK * (NBLK + 1) / 2)   // 2080 upper-triangle tiles
#define BK 64            // k-elems staged per step

typedef short v8s __attribute__((ext_vector_type(8)));   // 8 bf16 (4 VGPRs)
typedef float v4f __attribute__((ext_vector_type(4)));   // 4 fp32 acc

// async global->LDS, 16B per lane. LDS dest is wave-uniform base + lane*16.
__device__ __forceinline__ void gld16(const void* g, void* l) {
    __builtin_amdgcn_global_load_lds(
        (const __attribute__((address_space(1))) void*)g,
        (__attribute__((address_space(3))) void*)l, 16, 0, 0);
}

// ---------------------------------------------------------------------------
// Kernel 1: norms + positive dots (fp32), cast X -> bf16; also zeros rowsum.
// ---------------------------------------------------------------------------
__global__ __launch_bounds__(256) void prep_kernel(
        const float* __restrict__ x1, const float* __restrict__ x2,
        __hip_bfloat16* __restrict__ Xb, float* __restrict__ rnorm,
        float* __restrict__ posdot, float* __restrict__ rowsum) {
    const int t = threadIdx.x;
    if (t < 4) rowsum[blockIdx.x * 4 + t] = 0.f;   // 2048 blocks x 4 = NI
    const int sub = t >> 7;
    const int c4 = t & 127;
    const int i = blockIdx.x * 2 + sub;
    const float4 a = ((const float4*)(x1 + (size_t)i * DIM))[c4];
    const float4 b = ((const float4*)(x2 + (size_t)i * DIM))[c4];
    float s1 = a.x*a.x + a.y*a.y + a.z*a.z + a.w*a.w;
    float s2 = b.x*b.x + b.y*b.y + b.z*b.z + b.w*b.w;
    float dd = a.x*b.x + a.y*b.y + a.z*b.z + a.w*b.w;

    auto bfbits = [](float v) -> unsigned short {
        __hip_bfloat16 h = __float2bfloat16(v);
        return *(unsigned short*)&h;
    };
    ushort4 pa = { bfbits(a.x), bfbits(a.y), bfbits(a.z), bfbits(a.w) };
    ushort4 pb = { bfbits(b.x), bfbits(b.y), bfbits(b.z), bfbits(b.w) };
    ((ushort4*)(Xb + (size_t)i * DIM))[c4] = pa;
    ((ushort4*)(Xb + (size_t)(i + NS) * DIM))[c4] = pb;

    #pragma unroll
    for (int off = 32; off; off >>= 1) {
        s1 += __shfl_down(s1, off, 64);
        s2 += __shfl_down(s2, off, 64);
        dd += __shfl_down(dd, off, 64);
    }
    __shared__ float red[2][2][3];
    if ((t & 63) == 0) {
        const int w = (t >> 6) & 1;
        red[sub][w][0] = s1; red[sub][w][1] = s2; red[sub][w][2] = dd;
    }
    __syncthreads();
    if ((t & 127) == 0) {
        s1 = red[sub][0][0] + red[sub][1][0];
        s2 = red[sub][0][1] + red[sub][1][1];
        dd = red[sub][0][2] + red[sub][1][2];
        rnorm[i]      = 1.0f / sqrtf(s1);
        rnorm[i + NS] = 1.0f / sqrtf(s2);
        posdot[i] = dd;
    }
}

// ---------------------------------------------------------------------------
// Kernel 2: upper-triangle 128x128 tiles of G = Xb*Xb^T.
// Compact triangular 1D grid. BK=64 double-buffered LDS with async
// global_load_lds prefetch issued BEFORE compute, so the vmcnt(0) drain at
// the next barrier overlaps with this step's MFMAs.
// LDS tile layout: row stride 128B = 8 x 16B chunks, chunk slot = kc^(row&7)
// => ds_read_b128 fragments are 2-way bank-aliased (free).
// ---------------------------------------------------------------------------
__global__ __launch_bounds__(256, 2) void sim_kernel(
        const __hip_bfloat16* __restrict__ Xbh, const float* __restrict__ rnorm,
        float* __restrict__ rowsum, float* __restrict__ negpart) {
    // --- triangular decode: id -> (bi, bj), bi<=bj
    const int id = blockIdx.x;
    int bi = (int)((129.0f - sqrtf(16641.0f - 8.0f * (float)id)) * 0.5f);
    int base = bi * (129 - bi) / 2;
    if (id < base)                     { --bi; base = bi * (129 - bi) / 2; }
    else if (id >= base + (64 - bi))   { ++bi; base = bi * (129 - bi) / 2; }
    const int bj = bi + (id - base);
    const bool offdiag = (bj != bi);
    const int i0 = bi * 128, j0 = bj * 128;

    __shared__ short lds[2][2][128 * BK];      // [buf][A/B], 64 KB
    __shared__ float sRowAll[2][128];          // [wc][row]
    __shared__ float sColAll[2][128];          // [wr][col]
    __shared__ float sNeg[4];

    const int t = threadIdx.x;
    const int lane = t & 63, wv = t >> 6;
    const int wr = wv >> 1, wc = wv & 1;       // 2x2 waves, each 64x64
    const int r16 = lane & 15, quad = lane >> 4;

    const short* X = reinterpret_cast<const short*>(Xbh);

    // --- staging addresses: per wave 4 A-instrs + 4 B-instrs per stage.
    // instr q covers 64 chunks = 8 rows x 8 chunks; lane L -> chunk lin=c0+L,
    // row=lin>>3, slot cs=lin&7 holds global k-chunk kc = cs^(row&7).
    size_t gOffA[4], gOffB[4];
    int lOff[4];
    #pragma unroll
    for (int q = 0; q < 4; ++q) {
        const int lin = (wv * 4 + q) * 64 + lane;
        const int row = lin >> 3, cs = lin & 7;
        const int kc = cs ^ (row & 7);
        gOffA[q] = (size_t)(i0 + row) * DIM + kc * 8;
        gOffB[q] = (size_t)(j0 + row) * DIM + kc * 8;
        lOff[q] = (wv * 4 + q) * 512;          // shorts; HW adds lane*16B
    }

    // --- fragment LDS byte offsets (swizzled), substeps s2=0,1 (k-offset 32*s2)
    int offA[2][4], offB[2][4];
    #pragma unroll
    for (int s2 = 0; s2 < 2; ++s2)
        #pragma unroll
        for (int tt = 0; tt < 4; ++tt) {
            const int tra = wr * 64 + tt * 16 + r16;
            offA[s2][tt] = tra * 128 + (((s2 * 4 + quad) ^ (tra & 7)) * 16);
            const int trb = wc * 64 + tt * 16 + r16;
            offB[s2][tt] = trb * 128 + (((s2 * 4 + quad) ^ (trb & 7)) * 16);
        }

    v4f acc[4][4];
    #pragma unroll
    for (int a = 0; a < 4; ++a)
        #pragma unroll
        for (int b = 0; b < 4; ++b)
            acc[a][b] = (v4f){0.f, 0.f, 0.f, 0.f};

    // --- prologue: stage first chunk into buf0
    #pragma unroll
    for (int q = 0; q < 4; ++q) {
        gld16(X + gOffA[q], &lds[0][0][lOff[q]]);
        gld16(X + gOffB[q], &lds[0][1][lOff[q]]);
    }

    // --- main loop: 8 stages of BK=64
    for (int s = 0; s < DIM / BK; ++s) {
        const int cur = s & 1;
        __syncthreads();                       // buf[cur] complete (vmcnt drain)
        if (s + 1 < DIM / BK) {                // prefetch next (in flight during compute)
            const size_t k0 = (size_t)(s + 1) * BK;
            #pragma unroll
            for (int q = 0; q < 4; ++q) {
                gld16(X + gOffA[q] + k0, &lds[1 - cur][0][lOff[q]]);
                gld16(X + gOffB[q] + k0, &lds[1 - cur][1][lOff[q]]);
            }
        }
        const char* bufA = (const char*)&lds[cur][0][0];
        const char* bufB = (const char*)&lds[cur][1][0];
        #pragma unroll
        for (int s2 = 0; s2 < 2; ++s2) {
            v8s af[4], bf[4];
            #pragma unroll
            for (int tt = 0; tt < 4; ++tt) {
                af[tt] = *(const v8s*)(bufA + offA[s2][tt]);
                bf[tt] = *(const v8s*)(bufB + offB[s2][tt]);
            }
            #pragma unroll
            for (int ta = 0; ta < 4; ++ta)
                #pragma unroll
                for (int tb = 0; tb < 4; ++tb)
                    acc[ta][tb] = __builtin_amdgcn_mfma_f32_16x16x32_bf16(
                        af[ta], bf[tb], acc[ta][tb], 0, 0, 0);
        }
    }

    // --- epilogue: sim2 = 2*D*r_i*r_j; masked (j==i, j==i^NS) -> exp contributes 1
    float rc[4];
    int colg[4];
    #pragma unroll
    for (int tb = 0; tb < 4; ++tb) {
        colg[tb] = j0 + wc * 64 + tb * 16 + r16;
        rc[tb] = rnorm[colg[tb]];
    }
    float negacc = 0.f;
    float colacc[4] = {0.f, 0.f, 0.f, 0.f};
    #pragma unroll
    for (int ta = 0; ta < 4; ++ta) {
        #pragma unroll
        for (int r = 0; r < 4; ++r) {
            const int rowl = wr * 64 + ta * 16 + quad * 4 + r;
            const int rowg = i0 + rowl;
            const float rr = rnorm[rowg] * TEMP_INV;
            float rowe = 0.f;
            #pragma unroll
            for (int tb = 0; tb < 4; ++tb) {
                const float sim2 = acc[ta][tb][r] * rr * rc[tb];
                const bool masked = (colg[tb] == rowg) || (colg[tb] == (rowg ^ NS));
                const float e = masked ? 1.0f : __expf(sim2);
                rowe   += e;
                negacc += masked ? 0.0f : sim2;
                colacc[tb] += e;
            }
            #pragma unroll
            for (int off = 1; off < 16; off <<= 1)
                rowe += __shfl_xor(rowe, off, 64);
            if (r16 == 0) sRowAll[wc][rowl] = rowe;
        }
    }
    #pragma unroll
    for (int tb = 0; tb < 4; ++tb) {
        colacc[tb] += __shfl_xor(colacc[tb], 16, 64);
        colacc[tb] += __shfl_xor(colacc[tb], 32, 64);
        if (quad == 0) sColAll[wr][wc * 64 + tb * 16 + r16] = colacc[tb];
    }
    if (offdiag) negacc *= 2.0f;
    #pragma unroll
    for (int off = 1; off < 64; off <<= 1)
        negacc += __shfl_xor(negacc, off, 64);
    if (lane == 0) sNeg[wv] = negacc;

    __syncthreads();

    if (t < 128) {
        atomicAdd(&rowsum[i0 + t], sRowAll[0][t] + sRowAll[1][t]);
        if (offdiag)
            atomicAdd(&rowsum[j0 + t], sColAll[0][t] + sColAll[1][t]);
    }
    if (t == 0)
        negpart[id] = sNeg[0] + sNeg[1] + sNeg[2] + sNeg[3];
}

// ---------------------------------------------------------------------------
// Kernel 3: final scalars. E_i = rowsum[i] (includes +2 from masked entries).
// ---------------------------------------------------------------------------
__global__ __launch_bounds__(1024) void final_kernel(
        const float* __restrict__ rowsum, const float* __restrict__ rnorm,
        const float* __restrict__ posdot, const float* __restrict__ negpart,
        float* __restrict__ out) {
    const int t = threadIdx.x;
    float lsum = 0.f, psum = 0.f, nsum = 0.f;
    #pragma unroll
    for (int i = t; i < NI; i += 1024) {
        const int s = i & (NS - 1);
        const float sp = posdot[s] * rnorm[i] * rnorm[i ^ NS] * TEMP_INV;
        const float E = rowsum[i];
        lsum += logf(expf(sp) + E) - sp;
        psum += sp;
    }
    for (int i = t; i < NTRI; i += 1024)
        nsum += negpart[i];
    __shared__ float red[3][16];
    #pragma unroll
    for (int off = 32; off; off >>= 1) {
        lsum += __shfl_down(lsum, off, 64);
        psum += __shfl_down(psum, off, 64);
        nsum += __shfl_down(nsum, off, 64);
    }
    if ((t & 63) == 0) {
        red[0][t >> 6] = lsum; red[1][t >> 6] = psum; red[2][t >> 6] = nsum;
    }
    __syncthreads();
    if (t == 0) {
        lsum = 0.f; psum = 0.f; nsum = 0.f;
        #pragma unroll
        for (int w = 0; w < 16; ++w) {
            lsum += red[0][w]; psum += red[1][w]; nsum += red[2][w];
        }
        out[0] = lsum / (float)NI;
        out[1] = psum / (float)NI;
        out[2] = nsum / ((float)NI * (float)(NI - 2));
    }
}

// ---------------------------------------------------------------------------
extern "C" void kernel_launch(void* const* d_in, const int* in_sizes, int n_in,
                              void* d_out, int out_size, void* d_ws, size_t ws_size,
                              hipStream_t stream) {
    const float* x1 = (const float*)d_in[0];
    const float* x2 = (const float*)d_in[1];
    float* out = (float*)d_out;

    char* ws = (char*)d_ws;
    __hip_bfloat16* Xb = (__hip_bfloat16*)ws;                 // NI*DIM*2 = 8 MB
    float* rnorm  = (float*)(ws + (size_t)NI * DIM * 2);      // NI
    float* posdot = rnorm + NI;                               // NS
    float* rowsum = posdot + NS;                              // NI (zeroed in prep)
    float* negpart = rowsum + NI;                             // NTRI (all written)

    prep_kernel<<<NS / 2, 256, 0, stream>>>(x1, x2, Xb, rnorm, posdot, rowsum);

    sim_kernel<<<NTRI, 256, 0, stream>>>(Xb, rnorm, rowsum, negpart);

    final_kernel<<<1, 1024, 0, stream>>>(rowsum, rnorm, posdot, negpart, out);
}